// Round 1
// baseline (59.306 us; speedup 1.0000x reference)
//
#include <hip/hip_runtime.h>
#include <math.h>

#define BB 4
#define NN 512
#define PP 2048
#define EE 32768
#define FH 128
#define DRBF 32
#define INDIM (DRBF + 3*FH)   // 416
#define CUT 4.0f
#define PI_F 3.14159265358979323846f

struct __align__(16) Rec { float dx, dy, dz; unsigned int ap; };

// Pass 1: compute per-edge displacement/distance, compact survivors (dist < CUTOFF).
__global__ __launch_bounds__(256) void filter_kernel(
    const int* __restrict__ pe,        // (B,E,2) int32: [atom_loc, probe_loc]
    const float* __restrict__ pdisp,   // (B,E,3)
    const float* __restrict__ cell,    // (B,3,3)
    const float* __restrict__ atom_xyz,// (B,N,3)
    const float* __restrict__ probe_xyz,// (B,P,3)
    int* __restrict__ cnt,
    Rec* __restrict__ recs) {
  int idx = blockIdx.x * blockDim.x + threadIdx.x;
  const int total = BB * EE;
  for (int e = idx; e < total; e += gridDim.x * blockDim.x) {
    int b = e >> 15;                   // E = 32768 = 2^15
    int a_loc = pe[e*2];
    int p_loc = pe[e*2 + 1];
    float pd0 = pdisp[e*3], pd1 = pdisp[e*3+1], pd2 = pdisp[e*3+2];
    const float* cb = cell + b*9;
    float d0 = pd0*cb[0] + pd1*cb[3] + pd2*cb[6];
    float d1 = pd0*cb[1] + pd1*cb[4] + pd2*cb[7];
    float d2 = pd0*cb[2] + pd1*cb[5] + pd2*cb[8];
    int ag = b*NN + a_loc;
    int pg = b*PP + p_loc;
    float dx = probe_xyz[pg*3]   - (atom_xyz[ag*3]   + d0);
    float dy = probe_xyz[pg*3+1] - (atom_xyz[ag*3+1] + d1);
    float dz = probe_xyz[pg*3+2] - (atom_xyz[ag*3+2] + d2);
    float dist = sqrtf(dx*dx + dy*dy + dz*dz);
    if (dist < CUT) {
      int i = atomicAdd(cnt, 1);
      Rec r; r.dx = dx; r.dy = dy; r.dz = dz;
      r.ap = ((unsigned)ag << 16) | (unsigned)pg;
      recs[i] = r;
    }
  }
}

// Pass 2: one wave per surviving edge. h -> silu(h@W1+b1) -> silu(@W2+b2) -> @W3+b3,
// weighted by cosine cutoff, atomically accumulated into out[p].
__global__ __launch_bounds__(512) void mlp_kernel(
    const Rec* __restrict__ recs, const int* __restrict__ cnt,
    const float* __restrict__ S,   // (B*N, 128)
    const float* __restrict__ V,   // (B*N, 3, 128)
    const float* __restrict__ W1, const float* __restrict__ b1,
    const float* __restrict__ W2, const float* __restrict__ b2,
    const float* __restrict__ W3, const float* __restrict__ b3,
    float* __restrict__ out) {
  __shared__ float hbuf[8][INDIM];   // 8 waves per 512-thread block
  const int lane = threadIdx.x & 63;
  const int wave = threadIdx.x >> 6;
  const int wgl  = blockIdx.x * 8 + wave;
  const int nw   = gridDim.x * 8;
  const int n    = *cnt;
  float* h = hbuf[wave];

  for (int i = wgl; i < n; i += nw) {
    Rec r = recs[i];
    unsigned a = r.ap >> 16;
    unsigned p = r.ap & 0xffffu;
    float dist = sqrtf(r.dx*r.dx + r.dy*r.dy + r.dz*r.dz);
    float inv = 1.0f / (dist + 1e-8f);
    float rh0 = r.dx*inv, rh1 = r.dy*inv, rh2 = r.dz*inv;

    // e_pi: lanes 0..31
    if (lane < DRBF) {
      h[lane] = sinf(dist * (float)(lane + 1) * (PI_F / CUT)) / dist;
    }
    // q_pi, n_e, S gather: each lane covers features lane and lane+64
    #pragma unroll
    for (int t = 0; t < 2; ++t) {
      int f = lane + t*64;
      float v0 = V[(a*3 + 0)*FH + f];
      float v1 = V[(a*3 + 1)*FH + f];
      float v2 = V[(a*3 + 2)*FH + f];
      h[DRBF + f]        = v0*rh0 + v1*rh1 + v2*rh2;
      h[DRBF + FH + f]   = sqrtf(v0*v0 + v1*v1 + v2*v2);
      h[DRBF + 2*FH + f] = S[a*FH + f];
    }
    __threadfence_block();   // wave-internal LDS write->read visibility

    // Layer 1: lane computes features lane and lane+64 (f32, W1 from L2)
    float acc0 = b1[lane], acc1 = b1[lane + 64];
    #pragma unroll 8
    for (int k = 0; k < INDIM; ++k) {
      float hk = h[k];                 // wave-uniform broadcast read
      acc0 += hk * W1[k*FH + lane];
      acc1 += hk * W1[k*FH + lane + 64];
    }
    float h1a = acc0 / (1.0f + __expf(-acc0));
    float h1b = acc1 / (1.0f + __expf(-acc1));
    __threadfence_block();   // all lanes done reading h before overwrite
    h[lane] = h1a;
    h[lane + 64] = h1b;
    __threadfence_block();

    // Layer 2: lane computes output feature `lane` of 64
    float acc = b2[lane];
    #pragma unroll 8
    for (int k = 0; k < FH; ++k) {
      acc += h[k] * W2[k*64 + lane];
    }
    float h2 = acc / (1.0f + __expf(-acc));

    // Layer 3: dot over the 64 lanes
    float rsum = h2 * W3[lane];
    #pragma unroll
    for (int off = 32; off; off >>= 1) rsum += __shfl_xor(rsum, off, 64);

    if (lane == 0) {
      float m = rsum + b3[0];
      float cw = 0.5f * (cosf(PI_F * dist * (1.0f/CUT)) + 1.0f);
      atomicAdd(&out[p], m * cw);
    }
  }
}

extern "C" void kernel_launch(void* const* d_in, const int* in_sizes, int n_in,
                              void* d_out, int out_size, void* d_ws, size_t ws_size,
                              hipStream_t stream) {
  const float* S         = (const float*)d_in[0];
  const float* V         = (const float*)d_in[1];
  const float* atom_xyz  = (const float*)d_in[2];
  const float* probe_xyz = (const float*)d_in[3];
  const float* cell      = (const float*)d_in[4];
  const float* pdisp     = (const float*)d_in[5];
  const float* W1        = (const float*)d_in[6];
  const float* b1        = (const float*)d_in[7];
  const float* W2        = (const float*)d_in[8];
  const float* b2        = (const float*)d_in[9];
  const float* W3        = (const float*)d_in[10];
  const float* b3        = (const float*)d_in[11];
  const int*   pe        = (const int*)d_in[12];
  float* out = (float*)d_out;

  int* cnt  = (int*)d_ws;
  Rec* recs = (Rec*)((char*)d_ws + 16);

  hipMemsetAsync(d_out, 0, (size_t)out_size * sizeof(float), stream);
  hipMemsetAsync(d_ws, 0, 16, stream);

  filter_kernel<<<512, 256, 0, stream>>>(pe, pdisp, cell, atom_xyz, probe_xyz, cnt, recs);
  mlp_kernel<<<128, 512, 0, stream>>>(recs, cnt, S, V, W1, b1, W2, b2, W3, b3, out);
}

// Round 2
// 42.561 us; speedup vs baseline: 1.3935x; 1.3935x over previous
//
#include <hip/hip_runtime.h>
#include <math.h>

#define BB 4
#define NN 512
#define PP 2048
#define EE 32768
#define FH 128
#define DRBF 32
#define INDIM (DRBF + 3*FH)   // 416
#define CUT 4.0f
#define PI_F 3.14159265358979323846f

struct __align__(16) Rec { float dx, dy, dz; unsigned int ap; };

// Pass 1: compute per-edge displacement/distance, compact survivors (dist < CUTOFF).
__global__ __launch_bounds__(256) void filter_kernel(
    const int* __restrict__ pe,        // (B,E,2) int32: [atom_loc, probe_loc]
    const float* __restrict__ pdisp,   // (B,E,3)
    const float* __restrict__ cell,    // (B,3,3)
    const float* __restrict__ atom_xyz,// (B,N,3)
    const float* __restrict__ probe_xyz,// (B,P,3)
    int* __restrict__ cnt,
    Rec* __restrict__ recs) {
  int idx = blockIdx.x * blockDim.x + threadIdx.x;
  const int total = BB * EE;
  for (int e = idx; e < total; e += gridDim.x * blockDim.x) {
    int b = e >> 15;                   // E = 32768 = 2^15
    int a_loc = pe[e*2];
    int p_loc = pe[e*2 + 1];
    float pd0 = pdisp[e*3], pd1 = pdisp[e*3+1], pd2 = pdisp[e*3+2];
    const float* cb = cell + b*9;
    float d0 = pd0*cb[0] + pd1*cb[3] + pd2*cb[6];
    float d1 = pd0*cb[1] + pd1*cb[4] + pd2*cb[7];
    float d2 = pd0*cb[2] + pd1*cb[5] + pd2*cb[8];
    int ag = b*NN + a_loc;
    int pg = b*PP + p_loc;
    float dx = probe_xyz[pg*3]   - (atom_xyz[ag*3]   + d0);
    float dy = probe_xyz[pg*3+1] - (atom_xyz[ag*3+1] + d1);
    float dz = probe_xyz[pg*3+2] - (atom_xyz[ag*3+2] + d2);
    float dist = sqrtf(dx*dx + dy*dy + dz*dz);
    if (dist < CUT) {
      int i = atomicAdd(cnt, 1);
      Rec r; r.dx = dx; r.dy = dy; r.dz = dz;
      r.ap = ((unsigned)ag << 16) | (unsigned)pg;
      recs[i] = r;
    }
  }
}

// Pass 2: each wave processes a batch of 4 edges (shared W1/W2 loads amortize
// the L2-latency chain 4x; float2 weight loads halve the load count).
__global__ __launch_bounds__(256) void mlp_kernel(
    const Rec* __restrict__ recs, const int* __restrict__ cnt,
    const float* __restrict__ S,   // (B*N, 128)
    const float* __restrict__ V,   // (B*N, 3, 128)
    const float* __restrict__ W1, const float* __restrict__ b1,
    const float* __restrict__ W2, const float* __restrict__ b2,
    const float* __restrict__ W3, const float* __restrict__ b3,
    float* __restrict__ out) {
  __shared__ float hbuf[4][4][INDIM];   // [wave][edge][feature] = 26.6 KB
  const int lane = threadIdx.x & 63;
  const int wave = threadIdx.x >> 6;
  // wave-major global index: spreads the ~326 active batch-waves across all CUs
  const int wgl = wave * gridDim.x + blockIdx.x;
  const int nw  = gridDim.x * 4;
  const int n   = *cnt;
  const int nbatch = (n + 3) >> 2;
  float (*h)[INDIM] = hbuf[wave];
  const float2* W1f2 = (const float2*)W1;
  const float2* Vf2  = (const float2*)V;
  const float2* Sf2  = (const float2*)S;

  for (int bt = wgl; bt < nbatch; bt += nw) {
    const int e0 = bt << 2;
    float cwv[4]; unsigned pv[4];

    // Gather: build h[j][0..415] for 4 edges
    #pragma unroll
    for (int j = 0; j < 4; ++j) {
      int e = e0 + j;
      Rec r;
      if (e < n) { r = recs[e]; }
      else       { r.dx = 1.0f; r.dy = 0.0f; r.dz = 0.0f; r.ap = 0x0000FFFFu; }
      unsigned a = r.ap >> 16;
      pv[j] = r.ap & 0xFFFFu;            // 0xFFFF = dummy sentinel
      float d = sqrtf(r.dx*r.dx + r.dy*r.dy + r.dz*r.dz);
      float inv = 1.0f / (d + 1e-8f);
      float rh0 = r.dx*inv, rh1 = r.dy*inv, rh2 = r.dz*inv;
      cwv[j] = 0.5f * (cosf((PI_F/CUT) * d) + 1.0f);
      if (lane < DRBF) h[j][lane] = sinf(d * (float)(lane+1) * (PI_F/CUT)) / d;
      float2 v0 = Vf2[(a*3+0)*64 + lane];
      float2 v1 = Vf2[(a*3+1)*64 + lane];
      float2 v2 = Vf2[(a*3+2)*64 + lane];
      float2 sj = Sf2[a*64 + lane];
      float2 q;  q.x  = v0.x*rh0 + v1.x*rh1 + v2.x*rh2;
                 q.y  = v0.y*rh0 + v1.y*rh1 + v2.y*rh2;
      float2 nv; nv.x = sqrtf(v0.x*v0.x + v1.x*v1.x + v2.x*v2.x);
                 nv.y = sqrtf(v0.y*v0.y + v1.y*v1.y + v2.y*v2.y);
      *(float2*)&h[j][DRBF        + 2*lane] = q;
      *(float2*)&h[j][DRBF +   FH + 2*lane] = nv;
      *(float2*)&h[j][DRBF + 2*FH + 2*lane] = sj;
    }
    __threadfence_block();   // drain LDS writes before cross-lane reads

    // Layer 1: lane owns features {2l, 2l+1}; 4 edges share each W1 load
    float2 bb = ((const float2*)b1)[lane];
    float a0[4], a1[4];
    #pragma unroll
    for (int j = 0; j < 4; ++j) { a0[j] = bb.x; a1[j] = bb.y; }
    #pragma unroll 8
    for (int k = 0; k < INDIM; ++k) {
      float2 w = W1f2[k*64 + lane];
      #pragma unroll
      for (int j = 0; j < 4; ++j) {
        float hk = h[j][k];
        a0[j] = fmaf(hk, w.x, a0[j]);
        a1[j] = fmaf(hk, w.y, a1[j]);
      }
    }
    __threadfence_block();   // all h reads done before overwrite

    #pragma unroll
    for (int j = 0; j < 4; ++j) {
      float2 hv;
      hv.x = a0[j] / (1.0f + __expf(-a0[j]));
      hv.y = a1[j] / (1.0f + __expf(-a1[j]));
      *(float2*)&h[j][2*lane] = hv;
    }
    __threadfence_block();

    // Layer 2: lane owns output feature `lane` (64 outputs)
    float b2v = b2[lane];
    float acc2[4];
    #pragma unroll
    for (int j = 0; j < 4; ++j) acc2[j] = b2v;
    #pragma unroll 8
    for (int k = 0; k < FH; ++k) {
      float w = W2[k*64 + lane];
      #pragma unroll
      for (int j = 0; j < 4; ++j) acc2[j] = fmaf(h[j][k], w, acc2[j]);
    }

    // Layer 3: dot over 64 lanes + cutoff weight + scatter-add
    float w3  = W3[lane];
    float b3v = b3[0];
    #pragma unroll
    for (int j = 0; j < 4; ++j) {
      float h2 = acc2[j] / (1.0f + __expf(-acc2[j]));
      float r = h2 * w3;
      #pragma unroll
      for (int off = 32; off; off >>= 1) r += __shfl_xor(r, off, 64);
      if (lane == 0 && pv[j] != 0xFFFFu) {
        atomicAdd(&out[pv[j]], (r + b3v) * cwv[j]);
      }
    }
  }
}

extern "C" void kernel_launch(void* const* d_in, const int* in_sizes, int n_in,
                              void* d_out, int out_size, void* d_ws, size_t ws_size,
                              hipStream_t stream) {
  const float* S         = (const float*)d_in[0];
  const float* V         = (const float*)d_in[1];
  const float* atom_xyz  = (const float*)d_in[2];
  const float* probe_xyz = (const float*)d_in[3];
  const float* cell      = (const float*)d_in[4];
  const float* pdisp     = (const float*)d_in[5];
  const float* W1        = (const float*)d_in[6];
  const float* b1        = (const float*)d_in[7];
  const float* W2        = (const float*)d_in[8];
  const float* b2        = (const float*)d_in[9];
  const float* W3        = (const float*)d_in[10];
  const float* b3        = (const float*)d_in[11];
  const int*   pe        = (const int*)d_in[12];
  float* out = (float*)d_out;

  int* cnt  = (int*)d_ws;
  Rec* recs = (Rec*)((char*)d_ws + 16);

  hipMemsetAsync(d_out, 0, (size_t)out_size * sizeof(float), stream);
  hipMemsetAsync(d_ws, 0, 16, stream);

  filter_kernel<<<512, 256, 0, stream>>>(pe, pdisp, cell, atom_xyz, probe_xyz, cnt, recs);
  mlp_kernel<<<256, 256, 0, stream>>>(recs, cnt, S, V, W1, b1, W2, b2, W3, b3, out);
}